// Round 4
// baseline (543.521 us; speedup 1.0000x reference)
//
#include <hip/hip_runtime.h>

// DesignerNetwork: B=1024 batch-independent graph-GRU network.
// Round 4: pk_fma (float2 / v_pk_fma_f32) on all hot matvec loops with k
// padded 60->64; single overlaid state buffer (psi in two passes) shrinking
// LDS 35.8->27.3KB; __launch_bounds__(256,4) for >=4 blocks/CU.

namespace {

typedef float v2f __attribute__((ext_vector_type(2)));

constexpr int Bc = 1024;   // batch
constexpr int Nn = 32;     // nodes
constexpr int SP = 60;     // S_PHI == S_RHO
constexpr int NA = 5;      // actions
constexpr int NR = 7;      // roles

// ---- LDS layout (float offsets) ----
constexpr int OFF_ST   = 0;                     // states [32][64] (fwd then bwd)
constexpr int OFF_PART = OFF_ST + Nn * 64;      // partials [2][4][64][4]
constexpr int OFF_ZDZ  = OFF_PART + 2048;       // z/dz staged [32][20]
constexpr int OFF_PSI  = OFF_ZDZ + Nn * 20;     // psi raw [32][8]
constexpr int OFF_WU   = OFF_PSI + Nn * 8;      // Wu 7x120
constexpr int OFF_WA   = OFF_WU + 840;          // Wa 5x120
constexpr int OFF_WC   = OFF_WA + 600;          // Wc 120
constexpr int OFF_BA   = OFF_WC + 120;          // ba (pad 8)
constexpr int OFF_BU   = OFF_BA + 8;            // bu (pad 8)
constexpr int OFF_BC   = OFF_BU + 8;            // bc (pad 4)
constexpr int OFF_HAS  = OFF_BC + 4;            // has[32]
constexpr int OFF_AF   = OFF_HAS + 32;          // alpha_f [64] (even offset)
constexpr int OFF_AB   = OFF_AF + 64;           // alpha_b [64]
constexpr int OFF_OS   = OFF_AB + 64;           // omega scratch [8]
constexpr int OFF_MASK = OFF_OS + 8;            // uints: succ[32] pred[32] flags[4]
constexpr int LDS_FLOATS = OFF_MASK + 68 + 8;

__device__ __forceinline__ float sigm(float x) {
    return 1.0f / (1.0f + __expf(-x));
}

__device__ __forceinline__ float tanh_f(float x) {
    float e = __expf(fminf(2.0f * x, 80.0f));
    return (e - 1.0f) / (e + 1.0f);
}

// adj may arrive as int32 (0/1), packed uint8 bool, or float32. mode: 0/1/2.
__device__ __forceinline__ unsigned adj_nz(const unsigned* a, int mode, int r, int c) {
    const int idx = r * 32 + c;
    unsigned v = (mode == 1) ? ((a[idx >> 2] >> (8 * (idx & 3))) & 0xffu) : a[idx];
    return v != 0u ? 1u : 0u;
}

__device__ __forceinline__ float4 ldq(const float* lds, int par, int ww, int lane) {
    return *(const float4*)(lds + OFF_PART + ((par * 4 + ww) * 64 + lane) * 4);
}

// One cooperative GRU update of LDS h-vector hv (row stride 64, lanes 60..63
// always 0). gi partials (x-side) precomputed. All waves write identical hnew.
__device__ __forceinline__ void gru_coop(float* lds, float* hv,
        const v2f (&wh)[3][8], float gi0, float gi1, float gi2,
        float b0s, float b1s, float b2i, float b2h,
        int w, int lane, int& par) {
    v2f g0 = {0.f, 0.f}, g1 = {0.f, 0.f}, g2 = {0.f, 0.f};
    const v2f* hk = (const v2f*)(hv) + 8 * w;
#pragma unroll
    for (int p = 0; p < 8; ++p) {
        const v2f h = hk[p];
        g0 = __builtin_elementwise_fma(wh[0][p], h, g0);
        g1 = __builtin_elementwise_fma(wh[1][p], h, g1);
        g2 = __builtin_elementwise_fma(wh[2][p], h, g2);
    }
    const float hold = hv[lane];          // pre-barrier read of old state
    float4 q;
    q.x = gi0 + g0.x + g0.y;
    q.y = gi1 + g1.x + g1.y;
    q.z = gi2;
    q.w = g2.x + g2.y;
    *(float4*)(lds + OFF_PART + ((par * 4 + w) * 64 + lane) * 4) = q;
    __syncthreads();
    const float4 q0 = ldq(lds, par, 0, lane);
    const float4 q1 = ldq(lds, par, 1, lane);
    const float4 q2 = ldq(lds, par, 2, lane);
    const float4 q3 = ldq(lds, par, 3, lane);
    par ^= 1;
    const float a0  = q0.x + q1.x + q2.x + q3.x + b0s;
    const float a1  = q0.y + q1.y + q2.y + q3.y + b1s;
    const float a2i = q0.z + q1.z + q2.z + q3.z + b2i;
    const float a2h = q0.w + q1.w + q2.w + q3.w + b2h;
    const float r = sigm(a0);
    const float u = sigm(a1);
    const float n = tanh_f(fmaf(r, a2h, a2i));
    const float hnew = fmaf(u, hold - n, n);
    if (lane < SP) hv[lane] = hnew;       // every wave writes identical value
}

// x-side (gi) hoist: 3-gate dot of wx slice with row xv (64-wide, pad=0).
__device__ __forceinline__ void gi_hoist(const float* xv, const v2f (&wx)[3][8],
        int w, float& gi0, float& gi1, float& gi2) {
    v2f a0 = {0.f, 0.f}, a1 = {0.f, 0.f}, a2 = {0.f, 0.f};
    const v2f* xk = (const v2f*)(xv) + 8 * w;
#pragma unroll
    for (int p = 0; p < 8; ++p) {
        const v2f x = xk[p];
        a0 = __builtin_elementwise_fma(wx[0][p], x, a0);
        a1 = __builtin_elementwise_fma(wx[1][p], x, a1);
        a2 = __builtin_elementwise_fma(wx[2][p], x, a2);
    }
    gi0 = a0.x + a0.y; gi1 = a1.x + a1.y; gi2 = a2.x + a2.y;
}

__device__ __forceinline__ void load_weights(const float* __restrict__ Wih,
        const float* __restrict__ Whh, const float* __restrict__ bih,
        const float* __restrict__ bhh, const float* __restrict__ Wp,
        const float* __restrict__ bp, int w, int ln,
        v2f (&wh)[3][8], v2f (&wx)[3][8], v2f (&wp)[10],
        float& b0s, float& b1s, float& b2i, float& b2h, float& bpv) {
    const int kb = 16 * w;
#pragma unroll
    for (int g = 0; g < 3; ++g) {
        const float* hrow = Whh + (g * 60 + ln) * 60;
        const float* xrow = Wih + (g * 60 + ln) * 60;
#pragma unroll
        for (int p = 0; p < 8; ++p) {
            const int k0 = kb + 2 * p, k1 = k0 + 1;
            v2f hh, xx;
            hh.x = (k0 < 60) ? hrow[k0] : 0.f;
            hh.y = (k1 < 60) ? hrow[k1] : 0.f;
            xx.x = (k0 < 60) ? xrow[k0] : 0.f;
            xx.y = (k1 < 60) ? xrow[k1] : 0.f;
            wh[g][p] = hh; wx[g][p] = xx;
        }
    }
    const int pk = (w < 3) ? 20 * w : 60;     // waves 0-2: h part, wave 3: z/dz
    const float* prow = Wp + ln * 80 + pk;
#pragma unroll
    for (int p = 0; p < 10; ++p) { v2f t; t.x = prow[2*p]; t.y = prow[2*p+1]; wp[p] = t; }
    b0s = bih[ln] + bhh[ln];
    b1s = bih[60 + ln] + bhh[60 + ln];
    b2i = bih[120 + ln];
    b2h = bhh[120 + ln];
    bpv = bp[ln];
}

template <int FWD>
__device__ __forceinline__ void run_dir(float* lds,
        const v2f (&wh)[3][8], const v2f (&wx)[3][8], const v2f (&wp)[10],
        float b0s, float b1s, float b2i, float b2h, float bpv,
        int w, int lane, int& par) {
    float* st = lds + OFF_ST;
    const unsigned* succm = (const unsigned*)(lds + OFF_MASK);
    const unsigned* predm = succm + 32;

    for (int s = 0; s < Nn; ++s) {
        const int t = FWD ? s : (Nn - 1 - s);

        // ---- finalize rho[t]: cooperative proj over [h(60); z(10); dz(10)] ----
        v2f pa = {0.f, 0.f};
        const v2f* xb = (w < 3) ? ((const v2f*)(st + t * 64) + 10 * w)
                                : ((const v2f*)(lds + OFF_ZDZ + t * 20));
#pragma unroll
        for (int p = 0; p < 10; ++p)
            pa = __builtin_elementwise_fma(wp[p], xb[p], pa);
        lds[OFF_PART + ((par * 4 + w) * 64 + lane) * 4] = pa.x + pa.y;
        __syncthreads();
        float sum = lds[OFF_PART + ((par * 4 + 0) * 64 + lane) * 4]
                  + lds[OFF_PART + ((par * 4 + 1) * 64 + lane) * 4]
                  + lds[OFF_PART + ((par * 4 + 2) * 64 + lane) * 4]
                  + lds[OFF_PART + ((par * 4 + 3) * 64 + lane) * 4] + bpv;
        par ^= 1;
        const float rho = FWD ? tanh_f(sum) : sum;
        if (lane < SP) st[t * 64 + lane] = rho;   // replicated identical write

        // ---- GRU pushes to graph neighbors, gated by has[t] (block-uniform) ----
        const float hb = lds[OFF_HAS + t];
        unsigned m = FWD ? succm[t] : predm[t];
        if (hb != 0.f && m != 0u) {
            float gi0, gi1, gi2;
            gi_hoist(st + t * 64, wx, w, gi0, gi1, gi2);
            while (m) {
                const int i = __ffs(m) - 1;
                m &= m - 1u;
                gru_coop(lds, st + i * 64, wh, gi0, gi1, gi2,
                         b0s, b1s, b2i, b2h, w, lane, par);
            }
        }
    }

    // ---- alpha scan (this direction's weights + rho rows in st) ----
    float* ah = lds + (FWD ? OFF_AF : OFF_AB);
    ah[lane] = 0.f;                               // replicated identical write
    const int cnt = FWD ? 5 : 6;
    for (int s2 = 0; s2 < cnt; ++s2) {
        const int i = FWD ? (Nn - 5 + s2) : (5 - s2);
        if (lds[OFF_HAS + i] == 0.f) continue;    // block-uniform skip
        float gi0, gi1, gi2;
        gi_hoist(st + i * 64, wx, w, gi0, gi1, gi2);
        gru_coop(lds, ah, wh, gi0, gi1, gi2, b0s, b1s, b2i, b2h, w, lane, par);
    }
}

__device__ void run_heads(float* lds, int b, int lane, float* __restrict__ out) {
    const float* aF = lds + OFF_AF;
    const float* aB = lds + OFF_AB;

    float o = 0.f;
    if (lane < NA) {
        o = lds[OFF_BA + lane];
        const float* wa = lds + OFF_WA + lane * 120;
#pragma unroll
        for (int k = 0; k < SP; ++k) o = fmaf(wa[k], aF[k], o);
#pragma unroll
        for (int k = 0; k < SP; ++k) o = fmaf(wa[60 + k], aB[k], o);
        lds[OFF_OS + lane] = o;
    } else if (lane == NA) {
        float v = lds[OFF_BC];
        const float* wc = lds + OFF_WC;
#pragma unroll
        for (int k = 0; k < SP; ++k) v = fmaf(wc[k], aF[k], v);
#pragma unroll
        for (int k = 0; k < SP; ++k) v = fmaf(wc[60 + k], aB[k], v);
        out[Bc * NA + Bc * NR * Nn + b] = v;
    }
    __builtin_amdgcn_wave_barrier();

    if (lane < NA) {
        const float* os = lds + OFF_OS;
        float mx = os[0];
#pragma unroll
        for (int j = 1; j < NA; ++j) mx = fmaxf(mx, os[j]);
        float sum = 0.f;
#pragma unroll
        for (int j = 0; j < NA; ++j) sum += __expf(os[j] - mx);
        out[b * NA + lane] = __expf(o - mx) / sum;
    }

    if (lane < Nn) {
        const int i = lane;
        const float mk = lds[OFF_HAS + i];
        float p[NR];
        float mx = -1e30f;
#pragma unroll
        for (int c = 0; c < NR; ++c) {
            const float v = (mk != 0.f)
                ? (lds[OFF_PSI + i * 8 + c] + lds[OFF_BU + c])
                : -60.0f;
            p[c] = v;
            mx = fmaxf(mx, v);
        }
        float sum = 0.f;
#pragma unroll
        for (int c = 0; c < NR; ++c) { p[c] = __expf(p[c] - mx); sum += p[c]; }
        const float inv = 1.0f / sum;
#pragma unroll
        for (int c = 0; c < NR; ++c)
            out[Bc * NA + b * (NR * Nn) + c * Nn + i] = p[c] * inv;
    }
}

__global__ __launch_bounds__(256, 4)
void dn_kernel(const float* __restrict__ has, const float* __restrict__ z,
               const float* __restrict__ dz, const unsigned* __restrict__ adjw,
               const float* __restrict__ Wih_f, const float* __restrict__ Whh_f,
               const float* __restrict__ bih_f, const float* __restrict__ bhh_f,
               const float* __restrict__ Wih_b, const float* __restrict__ Whh_b,
               const float* __restrict__ bih_b, const float* __restrict__ bhh_b,
               const float* __restrict__ Wf, const float* __restrict__ bf,
               const float* __restrict__ Wb, const float* __restrict__ bb,
               const float* __restrict__ Wa, const float* __restrict__ ba,
               const float* __restrict__ Wc, const float* __restrict__ bc,
               const float* __restrict__ Wu, const float* __restrict__ bu,
               float* __restrict__ out) {
    __shared__ float lds[LDS_FLOATS];
    const int tid = threadIdx.x;
    const int lane = tid & 63;
    const int w = tid >> 6;
    const int b = blockIdx.x;
    const int ln = (lane < SP) ? lane : (SP - 1);   // clamp for weight/bias loads

    unsigned* succm = (unsigned*)(lds + OFF_MASK);
    unsigned* predm = succm + 32;
    unsigned* flags = predm + 32;

    if (tid < 4) flags[tid] = 0u;
    __syncthreads();

    // ---- adj dtype detection (first 256 words only) ----
    {
        unsigned ff = 0u, fb = 0u;
        for (int i = tid; i < 256; i += 256) {
            const unsigned v = adjw[i];
            ff |= (v == 0x3f800000u) ? 1u : 0u;
            fb |= (v > 1u && v != 0x3f800000u) ? 1u : 0u;
        }
        if (ff) atomicOr(&flags[0], 1u);
        if (fb) atomicOr(&flags[1], 1u);
    }

    // ---- stage head weights, has, z/dz; zero state array ----
    for (int i = tid; i < 840; i += 256) lds[OFF_WU + i] = Wu[i];
    for (int i = tid; i < 600; i += 256) lds[OFF_WA + i] = Wa[i];
    if (tid < 120) lds[OFF_WC + tid] = Wc[tid];
    if (tid < NR) lds[OFF_BU + tid] = bu[tid];
    if (tid < NA) lds[OFF_BA + tid] = ba[tid];
    if (tid == 0) lds[OFF_BC] = bc[0];
    if (tid < Nn) lds[OFF_HAS + tid] = has[b * 32 + tid];
    for (int i = tid; i < Nn * 20; i += 256) {
        const int t = i / 20, k = i - t * 20;
        lds[OFF_ZDZ + i] = (k < 10) ? z[(b * Nn + t) * 10 + k]
                                    : dz[(b * Nn + t) * 10 + (k - 10)];
    }
    for (int i = tid; i < Nn * 64; i += 256) lds[OFF_ST + i] = 0.f;
    __syncthreads();

    // ---- adjacency bitmasks ----
    const int mode = flags[0] ? 2 : (flags[1] ? 1 : 0);
    if (tid < 32) {
        unsigned sm = 0u;
        for (int c = 0; c < 32; ++c) sm |= adj_nz(adjw, mode, tid, c) << c;
        succm[tid] = sm;
    } else if (tid < 64) {
        const int c = tid - 32;
        unsigned pm = 0u;
        for (int r = 0; r < 32; ++r) pm |= adj_nz(adjw, mode, r, c) << r;
        predm[c] = pm;
    }
    __syncthreads();

    int par = 0;
    v2f wh[3][8], wx[3][8], wp[10];
    float b0s, b1s, b2i, b2h, bpv;

    // ---- forward direction ----
    load_weights(Wih_f, Whh_f, bih_f, bhh_f, Wf, bf, w, ln,
                 wh, wx, wp, b0s, b1s, b2i, b2h, bpv);
    run_dir<1>(lds, wh, wx, wp, b0s, b1s, b2i, b2h, bpv, w, lane, par);
    __syncthreads();

    // ---- psi pass 1 (fwd half) while rho_f still in ST ----
    if (tid < Nn * NR) {
        const int i = tid / NR, c = tid - i * NR;
        const float* wu = lds + OFF_WU + c * 120;
        const float* sf = lds + OFF_ST + i * 64;
        float acc = 0.f;
#pragma unroll
        for (int k = 0; k < SP; ++k) acc = fmaf(wu[k], sf[k], acc);
        lds[OFF_PSI + i * 8 + c] = acc;
    }
    __syncthreads();

    // ---- re-zero ST for backward direction ----
    for (int i = tid; i < Nn * 64; i += 256) lds[OFF_ST + i] = 0.f;
    __syncthreads();

    // ---- backward direction ----
    load_weights(Wih_b, Whh_b, bih_b, bhh_b, Wb, bb, w, ln,
                 wh, wx, wp, b0s, b1s, b2i, b2h, bpv);
    run_dir<0>(lds, wh, wx, wp, b0s, b1s, b2i, b2h, bpv, w, lane, par);
    __syncthreads();

    // ---- psi pass 2 (bwd half) ----
    if (tid < Nn * NR) {
        const int i = tid / NR, c = tid - i * NR;
        const float* wu = lds + OFF_WU + c * 120 + 60;
        const float* sb = lds + OFF_ST + i * 64;
        float acc = 0.f;
#pragma unroll
        for (int k = 0; k < SP; ++k) acc = fmaf(wu[k], sb[k], acc);
        lds[OFF_PSI + i * 8 + c] += acc;
    }
    __syncthreads();

    if (w == 0) run_heads(lds, b, lane, out);
}

}  // namespace

extern "C" void kernel_launch(void* const* d_in, const int* in_sizes, int n_in,
                              void* d_out, int out_size, void* d_ws, size_t ws_size,
                              hipStream_t stream) {
    (void)in_sizes; (void)n_in; (void)out_size; (void)d_ws; (void)ws_size;
    const float* has     = (const float*)d_in[0];
    const float* z       = (const float*)d_in[1];
    const float* dz      = (const float*)d_in[2];
    const unsigned* adjw = (const unsigned*)d_in[3];
    const float* Wih_f   = (const float*)d_in[4];
    const float* Whh_f   = (const float*)d_in[5];
    const float* bih_f   = (const float*)d_in[6];
    const float* bhh_f   = (const float*)d_in[7];
    const float* Wih_b   = (const float*)d_in[8];
    const float* Whh_b   = (const float*)d_in[9];
    const float* bih_b   = (const float*)d_in[10];
    const float* bhh_b   = (const float*)d_in[11];
    const float* Wf      = (const float*)d_in[12];
    const float* bf      = (const float*)d_in[13];
    const float* Wb      = (const float*)d_in[14];
    const float* bb      = (const float*)d_in[15];
    const float* Wa      = (const float*)d_in[16];
    const float* ba      = (const float*)d_in[17];
    const float* Wc      = (const float*)d_in[18];
    const float* bc      = (const float*)d_in[19];
    const float* Wu      = (const float*)d_in[20];
    const float* bu      = (const float*)d_in[21];
    float* out = (float*)d_out;

    dn_kernel<<<Bc, 256, 0, stream>>>(
        has, z, dz, adjw, Wih_f, Whh_f, bih_f, bhh_f,
        Wih_b, Whh_b, bih_b, bhh_b, Wf, bf, Wb, bb,
        Wa, ba, Wc, bc, Wu, bu, out);
}